// Round 1
// baseline (4734.505 us; speedup 1.0000x reference)
//
#include <hip/hip_runtime.h>
#include <math.h>

#define D 128
#define NF 10
#define N_IP 20000
#define N_CONN 100000
#define NE 200000
#define T_ROUNDS 3

// ---------------- utility kernels ----------------

__global__ void k_fill1(float* p, int n4) {
  int i = blockIdx.x * blockDim.x + threadIdx.x;
  if (i < n4) ((float4*)p)[i] = make_float4(1.f, 1.f, 1.f, 1.f);
}

__global__ void k_init_conn(float* __restrict__ cs, const float* __restrict__ feat) {
  int i = blockIdx.x * blockDim.x + threadIdx.x;  // over N_CONN*128
  if (i >= N_CONN * D) return;
  int r = i >> 7, j = i & 127;
  cs[i] = (j < NF) ? feat[r * NF + j] : 0.f;
}

__global__ void k_count(const int* __restrict__ d1, const int* __restrict__ d2,
                        int* __restrict__ c1, int* __restrict__ c2) {
  int e = blockIdx.x * blockDim.x + threadIdx.x;
  if (e >= NE) return;
  atomicAdd(&c1[d1[e]], 1);
  atomicAdd(&c2[d2[e]], 1);
}

// ---------------- tiled fp32 GEMM: C[M,Nc] = act(A[M,128] @ W[128,Nc] + bias) ----------------
// block 256 threads, 64x64 tile, 4x4 micro-tile, K chunked by 32.
template <int RELU>
__global__ void gemm128(const float* __restrict__ A, const float* __restrict__ W,
                        const float* __restrict__ bias, float* __restrict__ C,
                        int M, int Nc) {
  __shared__ float As[64][33];  // +1 pad
  __shared__ float Ws[32][65];  // +1 pad
  const int bm = blockIdx.x * 64, bn = blockIdx.y * 64;
  const int tid = threadIdx.x;
  const int tr = tid >> 4, tc = tid & 15;
  float acc[4][4] = {};
  for (int k0 = 0; k0 < 128; k0 += 32) {
#pragma unroll
    for (int i = 0; i < 2; i++) {  // A chunk: 64x32 = 512 float4
      int l = tid + i * 256;
      int r = l >> 3, c4 = (l & 7) << 2;
      int gr = bm + r;
      float4 v = make_float4(0, 0, 0, 0);
      if (gr < M) v = *(const float4*)(A + (size_t)gr * 128 + k0 + c4);
      As[r][c4] = v.x; As[r][c4 + 1] = v.y; As[r][c4 + 2] = v.z; As[r][c4 + 3] = v.w;
    }
#pragma unroll
    for (int i = 0; i < 2; i++) {  // W chunk: 32x64 = 512 float4
      int l = tid + i * 256;
      int r = l >> 4, c4 = (l & 15) << 2;
      float4 v = *(const float4*)(W + (size_t)(k0 + r) * Nc + bn + c4);
      Ws[r][c4] = v.x; Ws[r][c4 + 1] = v.y; Ws[r][c4 + 2] = v.z; Ws[r][c4 + 3] = v.w;
    }
    __syncthreads();
#pragma unroll
    for (int kk = 0; kk < 32; kk++) {
      float a[4], w[4];
#pragma unroll
      for (int i = 0; i < 4; i++) a[i] = As[tr * 4 + i][kk];
#pragma unroll
      for (int j = 0; j < 4; j++) w[j] = Ws[kk][tc * 4 + j];
#pragma unroll
      for (int i = 0; i < 4; i++)
#pragma unroll
        for (int j = 0; j < 4; j++) acc[i][j] += a[i] * w[j];
    }
    __syncthreads();
  }
#pragma unroll
  for (int i = 0; i < 4; i++) {
    int gr = bm + tr * 4 + i;
    if (gr >= M) continue;
#pragma unroll
    for (int j = 0; j < 4; j++) {
      int c = bn + tc * 4 + j;
      float v = acc[i][j];
      if (bias) v += bias[c];
      if (RELU) v = fmaxf(v, 0.f);
      C[(size_t)gr * Nc + c] = v;
    }
  }
}

// ---------------- edge combine + scatter: sum[dst] += relu(P[src]+Q[dst]+b) ----------------
__global__ void k_edge(const float* __restrict__ P, const float* __restrict__ Q,
                       const float* __restrict__ b, const int* __restrict__ src,
                       const int* __restrict__ dst, float* __restrict__ sum) {
  int idx = blockIdx.x * blockDim.x + threadIdx.x;  // NE*32 threads, 4 cols each
  int e = idx >> 5;
  if (e >= NE) return;
  int c4 = (idx & 31) << 2;
  int s = src[e], d = dst[e];
  float4 p = *(const float4*)(P + (size_t)s * D + c4);
  float4 q = *(const float4*)(Q + (size_t)d * D + c4);
  float4 bb = *(const float4*)(b + c4);
  float* sp = sum + (size_t)d * D + c4;
  atomicAdd(sp + 0, fmaxf(p.x + q.x + bb.x, 0.f));
  atomicAdd(sp + 1, fmaxf(p.y + q.y + bb.y, 0.f));
  atomicAdd(sp + 2, fmaxf(p.z + q.z + bb.z, 0.f));
  atomicAdd(sp + 3, fmaxf(p.w + q.w + bb.w, 0.f));
}

// ---------------- sum -> mean in place ----------------
__global__ void k_mean(float* __restrict__ sum, const int* __restrict__ cnt, int nrows) {
  int idx = blockIdx.x * blockDim.x + threadIdx.x;  // nrows*32
  if (idx >= nrows * 32) return;
  int r = idx >> 5, c4 = (idx & 31) << 2;
  float inv = 1.f / fmaxf((float)cnt[r], 1.f);
  float4* p = (float4*)(sum + (size_t)r * D + c4);
  float4 v = *p;
  v.x *= inv; v.y *= inv; v.z *= inv; v.w *= inv;
  *p = v;
}

// ---------------- GRU gate combine (in-place h update) ----------------
__global__ void k_gru(const float* __restrict__ xm, const float* __restrict__ hm,
                      float* __restrict__ h, int rows) {
  int idx = blockIdx.x * blockDim.x + threadIdx.x;  // rows*128
  if (idx >= rows * D) return;
  int r = idx >> 7, j = idx & 127;
  const float* xp = xm + (size_t)r * 384;
  const float* hp = hm + (size_t)r * 384;
  float xz = xp[j], xr = xp[128 + j], xh = xp[256 + j];
  float hz = hp[j], hr = hp[128 + j], hh = hp[256 + j];
  float z = 1.f / (1.f + expf(-(xz + hz)));
  float rr = 1.f / (1.f + expf(-(xr + hr)));
  float hc = tanhf(xh + rr * hh);
  float hold = h[idx];
  h[idx] = z * hold + (1.f - z) * hc;
}

// ---------------- fused final layer: logits + softmax ----------------
__global__ void k_readout(const float* __restrict__ h2, const float* __restrict__ W3,
                          const float* __restrict__ b3, float* __restrict__ out) {
  __shared__ float w[64 * 15];
  __shared__ float b[15];
  for (int l = threadIdx.x; l < 960; l += blockDim.x) w[l] = W3[l];
  if (threadIdx.x < 15) b[threadIdx.x] = b3[threadIdx.x];
  __syncthreads();
  int r = blockIdx.x * blockDim.x + threadIdx.x;
  if (r >= N_CONN) return;
  float hv[64];
  const float4* hp = (const float4*)(h2 + (size_t)r * 64);
#pragma unroll
  for (int i = 0; i < 16; i++) {
    float4 v = hp[i];
    hv[4 * i] = v.x; hv[4 * i + 1] = v.y; hv[4 * i + 2] = v.z; hv[4 * i + 3] = v.w;
  }
  float lg[15];
#pragma unroll
  for (int c = 0; c < 15; c++) lg[c] = b[c];
  for (int k = 0; k < 64; k++) {
    float hk = hv[k];
#pragma unroll
    for (int c = 0; c < 15; c++) lg[c] += hk * w[k * 15 + c];
  }
  float m = lg[0];
#pragma unroll
  for (int c = 1; c < 15; c++) m = fmaxf(m, lg[c]);
  float ssum = 0.f;
#pragma unroll
  for (int c = 0; c < 15; c++) { lg[c] = expf(lg[c] - m); ssum += lg[c]; }
  float inv = 1.f / ssum;
#pragma unroll
  for (int c = 0; c < 15; c++) out[(size_t)r * 15 + c] = lg[c] * inv;
}

// ---------------- launch ----------------
extern "C" void kernel_launch(void* const* d_in, const int* in_sizes, int n_in,
                              void* d_out, int out_size, void* d_ws, size_t ws_size,
                              hipStream_t stream) {
  const float* feat = (const float*)d_in[0];
  const int* src1 = (const int*)d_in[1];  // src_ip_to_connection  (ip idx)
  const int* dst1 = (const int*)d_in[2];  // dst_ip_to_connection  (conn idx, segment for ip_mean)
  const int* src2 = (const int*)d_in[3];  // src_connection_to_ip  (conn idx)
  const int* dst2 = (const int*)d_in[4];  // dst_connection_to_ip  (ip idx, segment for conn_mean)
  const float* Wm1 = (const float*)d_in[5];
  const float* bm1 = (const float*)d_in[6];
  const float* Wm2 = (const float*)d_in[7];
  const float* bm2 = (const float*)d_in[8];
  const float* gik = (const float*)d_in[9];
  const float* gir = (const float*)d_in[10];
  const float* gib = (const float*)d_in[11];
  const float* gck = (const float*)d_in[12];
  const float* gcr = (const float*)d_in[13];
  const float* gcb = (const float*)d_in[14];
  const float* Wr1 = (const float*)d_in[15];
  const float* br1 = (const float*)d_in[16];
  const float* Wr2 = (const float*)d_in[17];
  const float* br2 = (const float*)d_in[18];
  const float* Wr3 = (const float*)d_in[19];
  const float* br3 = (const float*)d_in[20];
  float* out = (float*)d_out;

  // workspace layout (floats); total 61,560,000 floats = 246.24 MB
  float* ws = (float*)d_ws;
  size_t o = 0;
  float* ip_state = ws + o;   o += (size_t)N_IP * D;    // 2.56M
  float* conn_state = ws + o; o += (size_t)N_CONN * D;  // 12.8M
  float* sum1 = ws + o;       o += (size_t)N_CONN * D;  // 12.8M (ip_mean accum)
  float* sum2 = ws + o;       o += (size_t)N_IP * D;    // 2.56M (conn_mean accum)
  int* cnt1 = (int*)(ws + o); o += N_CONN;
  int* cnt2 = (int*)(ws + o); o += N_IP;
  float* R = ws + o;  // overlay region: 30,720,000 floats
  // overlay 1 (message phase): P1,Q1,P2,Q2
  float* P1 = R;                           // N_IP*D
  float* Q1 = R + (size_t)N_IP * D;        // N_CONN*D
  float* P2 = Q1 + (size_t)N_CONN * D;     // N_CONN*D
  float* Q2 = P2 + (size_t)N_CONN * D;     // N_IP*D
  // overlay 2 (GRU phase): xm/hm chunks (max 40000 rows x 384)
  float* gm1 = R;
  float* gm2 = R + (size_t)40000 * 384;
  // overlay 3 (readout): h1, h2
  float* h1 = R;                           // N_CONN*128
  float* h2 = R + (size_t)N_CONN * D;      // N_CONN*64

  const int BT = 256;

  // init states + counts
  k_fill1<<<(N_IP * D / 4 + BT - 1) / BT, BT, 0, stream>>>(ip_state, N_IP * D / 4);
  k_init_conn<<<(N_CONN * D + BT - 1) / BT, BT, 0, stream>>>(conn_state, feat);
  hipMemsetAsync(cnt1, 0, (size_t)(N_CONN + N_IP) * sizeof(int), stream);
  k_count<<<(NE + BT - 1) / BT, BT, 0, stream>>>(dst1, dst2, cnt1, cnt2);

  dim3 gIP128((N_IP + 63) / 64, 2);
  dim3 gCN128((N_CONN + 63) / 64, 2);
  dim3 gIP384((N_IP + 63) / 64, 6);

  for (int t = 0; t < T_ROUNDS; t++) {
    // zero accumulators (sum1 and sum2 are contiguous)
    hipMemsetAsync(sum1, 0, (size_t)(N_CONN * D + N_IP * D) * sizeof(float), stream);

    // message precomputes: P = state @ W[:128], Q = state @ W[128:]
    gemm128<0><<<gIP128, 256, 0, stream>>>(ip_state, Wm1, nullptr, P1, N_IP, 128);
    gemm128<0><<<gCN128, 256, 0, stream>>>(conn_state, Wm1 + 128 * 128, nullptr, Q1, N_CONN, 128);
    gemm128<0><<<gCN128, 256, 0, stream>>>(conn_state, Wm2, nullptr, P2, N_CONN, 128);
    gemm128<0><<<gIP128, 256, 0, stream>>>(ip_state, Wm2 + 128 * 128, nullptr, Q2, N_IP, 128);

    // edge combine + scatter-add
    k_edge<<<NE * 32 / BT, BT, 0, stream>>>(P1, Q1, bm1, src1, dst1, sum1);
    k_edge<<<NE * 32 / BT, BT, 0, stream>>>(P2, Q2, bm2, src2, dst2, sum2);

    // sums -> means
    k_mean<<<(N_CONN * 32 + BT - 1) / BT, BT, 0, stream>>>(sum1, cnt1, N_CONN);
    k_mean<<<(N_IP * 32 + BT - 1) / BT, BT, 0, stream>>>(sum2, cnt2, N_IP);

    // GRU ip: x = conn_mean (sum2), h = ip_state
    gemm128<0><<<gIP384, 256, 0, stream>>>(sum2, gik, gib, gm1, N_IP, 384);
    gemm128<0><<<gIP384, 256, 0, stream>>>(ip_state, gir, gib + 384, gm2, N_IP, 384);
    k_gru<<<(N_IP * D + BT - 1) / BT, BT, 0, stream>>>(gm1, gm2, ip_state, N_IP);

    // GRU conn: x = ip_mean (sum1), h = conn_state — chunked to fit overlay scratch
    for (int base = 0; base < N_CONN; base += 40000) {
      int rows = (N_CONN - base < 40000) ? (N_CONN - base) : 40000;
      dim3 gc((rows + 63) / 64, 6);
      gemm128<0><<<gc, 256, 0, stream>>>(sum1 + (size_t)base * D, gck, gcb, gm1, rows, 384);
      gemm128<0><<<gc, 256, 0, stream>>>(conn_state + (size_t)base * D, gcr, gcb + 384, gm2, rows, 384);
      k_gru<<<(rows * D + BT - 1) / BT, BT, 0, stream>>>(gm1, gm2, conn_state + (size_t)base * D, rows);
    }
  }

  // readout
  gemm128<1><<<gCN128, 256, 0, stream>>>(conn_state, Wr1, br1, h1, N_CONN, 128);
  dim3 gH2((N_CONN + 63) / 64, 1);
  gemm128<1><<<gH2, 256, 0, stream>>>(h1, Wr2, br2, h2, N_CONN, 64);
  k_readout<<<(N_CONN + BT - 1) / BT, BT, 0, stream>>>(h2, Wr3, br3, out);
}

// Round 2
// 1799.943 us; speedup vs baseline: 2.6304x; 2.6304x over previous
//
#include <hip/hip_runtime.h>
#include <math.h>

#define D 128
#define NF 10
#define N_IP 20000
#define N_CONN 100000
#define NE 200000
#define T_ROUNDS 3

typedef unsigned short u16;
using bf16x8 = __attribute__((ext_vector_type(8))) short;
using floatx4 = __attribute__((ext_vector_type(4))) float;

__device__ inline u16 f2bf(float f) {
  union { float f; unsigned u; } v; v.f = f;
  unsigned u = v.u;
  return (u16)((u + 0x7fffu + ((u >> 16) & 1u)) >> 16);  // RNE
}

// ---------------- utility kernels ----------------

__global__ void k_fill1(float* p, int n4) {
  int i = blockIdx.x * blockDim.x + threadIdx.x;
  if (i < n4) ((float4*)p)[i] = make_float4(1.f, 1.f, 1.f, 1.f);
}

__global__ void k_init_conn(float* __restrict__ cs, const float* __restrict__ feat) {
  int i = blockIdx.x * blockDim.x + threadIdx.x;  // over N_CONN*128
  if (i >= N_CONN * D) return;
  int r = i >> 7, j = i & 127;
  cs[i] = (j < NF) ? feat[r * NF + j] : 0.f;
}

__global__ void k_count(const int* __restrict__ d1, const int* __restrict__ d2,
                        int* __restrict__ c1, int* __restrict__ c2) {
  int e = blockIdx.x * blockDim.x + threadIdx.x;
  if (e >= NE) return;
  atomicAdd(&c1[d1[e]], 1);
  atomicAdd(&c2[d2[e]], 1);
}

// single-block (1024 thr) exclusive scan: off[i] = sum(cnt[0..i))
__global__ void k_scan(const int* __restrict__ cnt, int* __restrict__ off, int n) {
  const int tid = threadIdx.x;
  const int chunk = (n + 1023) >> 10;
  int lo = tid * chunk;
  int hi = lo + chunk; if (hi > n) hi = n;
  int s = 0;
  for (int i = lo; i < hi; i++) s += cnt[i];
  __shared__ int wsum[16];
  int lane = tid & 63, wv = tid >> 6;
  int x = s;
  for (int d = 1; d < 64; d <<= 1) {
    int y = __shfl_up(x, d, 64);
    if (lane >= d) x += y;
  }
  if (lane == 63) wsum[wv] = x;
  __syncthreads();
  if (wv == 0 && lane < 16) {
    int y = wsum[lane];
    for (int d = 1; d < 16; d <<= 1) {
      int z = __shfl_up(y, d, 64);
      if (lane >= d) y += z;
    }
    wsum[lane] = y;  // inclusive scan of wave sums
  }
  __syncthreads();
  int run = (x - s) + (wv > 0 ? wsum[wv - 1] : 0);
  for (int i = lo; i < hi; i++) { off[i] = run; run += cnt[i]; }
}

__global__ void k_copyint(const int* __restrict__ a, int* __restrict__ b, int n) {
  int i = blockIdx.x * blockDim.x + threadIdx.x;
  if (i < n) b[i] = a[i];
}

// scatter src ids into dst-sorted order (both edge sets at once)
__global__ void k_scatter(const int* __restrict__ s1, const int* __restrict__ d1,
                          const int* __restrict__ s2, const int* __restrict__ d2,
                          int* __restrict__ cur1, int* __restrict__ cur2,
                          int* __restrict__ o1, int* __restrict__ o2) {
  int e = blockIdx.x * blockDim.x + threadIdx.x;
  if (e >= NE) return;
  int p1 = atomicAdd(&cur1[d1[e]], 1);
  o1[p1] = s1[e];
  int p2 = atomicAdd(&cur2[d2[e]], 1);
  o2[p2] = s2[e];
}

// ---------------- segment mean via gather: mean[n] = avg_e relu(P[src_e] + Q[n] + b) ----------------
__global__ void k_gather_mean(const float* __restrict__ P, const float* __restrict__ Q,
                              const float* __restrict__ bias, const int* __restrict__ srcs,
                              const int* __restrict__ off, const int* __restrict__ cnt,
                              float* __restrict__ outm, int nnodes) {
  int idx = blockIdx.x * blockDim.x + threadIdx.x;  // nnodes*32, 4 cols/lane
  int node = idx >> 5;
  if (node >= nnodes) return;
  int c4 = (idx & 31) << 2;
  float4 q = *(const float4*)(Q + (size_t)node * D + c4);
  float4 bb = *(const float4*)(bias + c4);
  float qx = q.x + bb.x, qy = q.y + bb.y, qz = q.z + bb.z, qw = q.w + bb.w;
  float ax = 0.f, ay = 0.f, az = 0.f, aw = 0.f;
  int o = off[node], n = cnt[node];
  for (int i = 0; i < n; i++) {
    int s = srcs[o + i];
    float4 p = *(const float4*)(P + (size_t)s * D + c4);
    ax += fmaxf(p.x + qx, 0.f);
    ay += fmaxf(p.y + qy, 0.f);
    az += fmaxf(p.z + qz, 0.f);
    aw += fmaxf(p.w + qw, 0.f);
  }
  float inv = 1.f / fmaxf((float)n, 1.f);
  *(float4*)(outm + (size_t)node * D + c4) =
      make_float4(ax * inv, ay * inv, az * inv, aw * inv);
}

// ---------------- bf16 MFMA GEMM: C[M,Nc] = act(A[M,128] @ W[128,Nc] + bias) ----------------
// A, W fp32 in global; converted to bf16 (RNE) during LDS staging; fp32 accumulate.
// block = 256 (4 waves), tile 64(M) x 64(N), full K=128 staged.
template <int RELU>
__global__ __launch_bounds__(256) void gemm_bf16(
    const float* __restrict__ A, const float* __restrict__ W,
    const float* __restrict__ bias, float* __restrict__ C, int M, int Nc) {
  constexpr int LDA = 136;  // 128 + 8 pad (u16) -> 272B row, 16B aligned, conflict-free-ish
  __shared__ __align__(16) u16 As[64 * LDA];
  __shared__ __align__(16) u16 Bs[64 * LDA];  // Bs[n][k] = W[k][bn+n]
  const int bm = blockIdx.x * 64, bn = blockIdx.y * 64;
  const int tid = threadIdx.x;
#pragma unroll
  for (int i = 0; i < 8; i++) {  // A: 64x128 = 2048 float4
    int l = tid + i * 256;
    int r = l >> 5, c4 = (l & 31) << 2;
    int gr = bm + r;
    float4 v = make_float4(0, 0, 0, 0);
    if (gr < M) v = *(const float4*)(A + (size_t)gr * 128 + c4);
    u16* p = As + r * LDA + c4;
    p[0] = f2bf(v.x); p[1] = f2bf(v.y); p[2] = f2bf(v.z); p[3] = f2bf(v.w);
  }
#pragma unroll
  for (int i = 0; i < 8; i++) {  // W: 128x64 = 2048 float4, transpose into Bs
    int l = tid + i * 256;
    int k = l >> 4, n4 = (l & 15) << 2;
    float4 v = *(const float4*)(W + (size_t)k * Nc + bn + n4);
    Bs[(n4 + 0) * LDA + k] = f2bf(v.x);
    Bs[(n4 + 1) * LDA + k] = f2bf(v.y);
    Bs[(n4 + 2) * LDA + k] = f2bf(v.z);
    Bs[(n4 + 3) * LDA + k] = f2bf(v.w);
  }
  __syncthreads();
  const int wv = tid >> 6, lane = tid & 63;
  const int lrow = lane & 15, quad = lane >> 4;
  floatx4 acc[4] = {{0,0,0,0},{0,0,0,0},{0,0,0,0},{0,0,0,0}};
  const u16* arow = As + (wv * 16 + lrow) * LDA + quad * 8;
#pragma unroll
  for (int ks = 0; ks < 4; ks++) {
    bf16x8 af = *(const bf16x8*)(arow + ks * 32);
#pragma unroll
    for (int nt = 0; nt < 4; nt++) {
      bf16x8 bfr = *(const bf16x8*)(Bs + (nt * 16 + lrow) * LDA + quad * 8 + ks * 32);
      acc[nt] = __builtin_amdgcn_mfma_f32_16x16x32_bf16(af, bfr, acc[nt], 0, 0, 0);
    }
  }
#pragma unroll
  for (int nt = 0; nt < 4; nt++) {
    int col = bn + nt * 16 + lrow;
    float bv = bias ? bias[col] : 0.f;
#pragma unroll
    for (int reg = 0; reg < 4; reg++) {
      int gr = bm + wv * 16 + quad * 4 + reg;
      if (gr < M) {
        float v = acc[nt][reg] + bv;
        if (RELU) v = fmaxf(v, 0.f);
        C[(size_t)gr * Nc + col] = v;
      }
    }
  }
}

// ---------------- GRU gate combine (in-place h update) ----------------
__global__ void k_gru(const float* __restrict__ xm, const float* __restrict__ hm,
                      float* __restrict__ h, int rows) {
  int idx = blockIdx.x * blockDim.x + threadIdx.x;  // rows*128
  if (idx >= rows * D) return;
  int r = idx >> 7, j = idx & 127;
  const float* xp = xm + (size_t)r * 384;
  const float* hp = hm + (size_t)r * 384;
  float xz = xp[j], xr = xp[128 + j], xh = xp[256 + j];
  float hz = hp[j], hr = hp[128 + j], hh = hp[256 + j];
  float z = 1.f / (1.f + expf(-(xz + hz)));
  float rr = 1.f / (1.f + expf(-(xr + hr)));
  float hc = tanhf(xh + rr * hh);
  float hold = h[idx];
  h[idx] = z * hold + (1.f - z) * hc;
}

// ---------------- fused final layer: logits + softmax ----------------
__global__ void k_readout(const float* __restrict__ h2, const float* __restrict__ W3,
                          const float* __restrict__ b3, float* __restrict__ out) {
  __shared__ float w[64 * 15];
  __shared__ float b[15];
  for (int l = threadIdx.x; l < 960; l += blockDim.x) w[l] = W3[l];
  if (threadIdx.x < 15) b[threadIdx.x] = b3[threadIdx.x];
  __syncthreads();
  int r = blockIdx.x * blockDim.x + threadIdx.x;
  if (r >= N_CONN) return;
  float hv[64];
  const float4* hp = (const float4*)(h2 + (size_t)r * 64);
#pragma unroll
  for (int i = 0; i < 16; i++) {
    float4 v = hp[i];
    hv[4 * i] = v.x; hv[4 * i + 1] = v.y; hv[4 * i + 2] = v.z; hv[4 * i + 3] = v.w;
  }
  float lg[15];
#pragma unroll
  for (int c = 0; c < 15; c++) lg[c] = b[c];
  for (int k = 0; k < 64; k++) {
    float hk = hv[k];
#pragma unroll
    for (int c = 0; c < 15; c++) lg[c] += hk * w[k * 15 + c];
  }
  float m = lg[0];
#pragma unroll
  for (int c = 1; c < 15; c++) m = fmaxf(m, lg[c]);
  float ssum = 0.f;
#pragma unroll
  for (int c = 0; c < 15; c++) { lg[c] = expf(lg[c] - m); ssum += lg[c]; }
  float inv = 1.f / ssum;
#pragma unroll
  for (int c = 0; c < 15; c++) out[(size_t)r * 15 + c] = lg[c] * inv;
}

// ---------------- launch ----------------
extern "C" void kernel_launch(void* const* d_in, const int* in_sizes, int n_in,
                              void* d_out, int out_size, void* d_ws, size_t ws_size,
                              hipStream_t stream) {
  const float* feat = (const float*)d_in[0];
  const int* src1 = (const int*)d_in[1];  // ip idx per edge
  const int* dst1 = (const int*)d_in[2];  // conn idx per edge (segment for ip_mean)
  const int* src2 = (const int*)d_in[3];  // conn idx per edge
  const int* dst2 = (const int*)d_in[4];  // ip idx per edge (segment for conn_mean)
  const float* Wm1 = (const float*)d_in[5];
  const float* bm1 = (const float*)d_in[6];
  const float* Wm2 = (const float*)d_in[7];
  const float* bm2 = (const float*)d_in[8];
  const float* gik = (const float*)d_in[9];
  const float* gir = (const float*)d_in[10];
  const float* gib = (const float*)d_in[11];
  const float* gck = (const float*)d_in[12];
  const float* gcr = (const float*)d_in[13];
  const float* gcb = (const float*)d_in[14];
  const float* Wr1 = (const float*)d_in[15];
  const float* br1 = (const float*)d_in[16];
  const float* Wr2 = (const float*)d_in[17];
  const float* br2 = (const float*)d_in[18];
  const float* Wr3 = (const float*)d_in[19];
  const float* br3 = (const float*)d_in[20];
  float* out = (float*)d_out;

  // ---- workspace layout ----
  float* ws = (float*)d_ws;
  size_t o = 0;
  float* ip_state = ws + o;   o += (size_t)N_IP * D;    // 2.56M f
  float* conn_state = ws + o; o += (size_t)N_CONN * D;  // 12.8M f
  float* sum1 = ws + o;       o += (size_t)N_CONN * D;  // 12.8M f (ip_mean)
  float* sum2 = ws + o;       o += (size_t)N_IP * D;    // 2.56M f (conn_mean)
  const int CHUNK = 32768;
  float* R = ws + o;          o += (size_t)2 * CHUNK * 384;  // 25.17M f overlay
  // overlay A (message phase 1): P1, Q1
  float* P1 = R;                        // N_IP*D
  float* Q1 = R + (size_t)N_IP * D;     // N_CONN*D
  // overlay B (message phase 2): P2, Q2
  float* P2 = R;                        // N_CONN*D
  float* Q2 = R + (size_t)N_CONN * D;   // N_IP*D
  // overlay C (GRU): gm1, gm2 chunks
  float* gm1 = R;
  float* gm2 = R + (size_t)CHUNK * 384;
  // overlay D (readout): h1, h2
  float* h1 = R;
  float* h2 = R + (size_t)N_CONN * D;
  // int region (CSR)
  int* ip = (int*)(ws + o);
  int* cnt1 = ip;                 ip += N_CONN;
  int* cnt2 = ip;                 ip += N_IP;
  int* off1 = ip;                 ip += N_CONN;
  int* off2 = ip;                 ip += N_IP;
  int* cur1 = ip;                 ip += N_CONN;
  int* cur2 = ip;                 ip += N_IP;
  int* srcs1 = ip;                ip += NE;
  int* srcs2 = ip;                ip += NE;

  const int BT = 256;

  // ---- init states ----
  k_fill1<<<(N_IP * D / 4 + BT - 1) / BT, BT, 0, stream>>>(ip_state, N_IP * D / 4);
  k_init_conn<<<(N_CONN * D + BT - 1) / BT, BT, 0, stream>>>(conn_state, feat);

  // ---- build CSR (once per launch; same work every call) ----
  hipMemsetAsync(cnt1, 0, (size_t)(N_CONN + N_IP) * sizeof(int), stream);
  k_count<<<(NE + BT - 1) / BT, BT, 0, stream>>>(dst1, dst2, cnt1, cnt2);
  k_scan<<<1, 1024, 0, stream>>>(cnt1, off1, N_CONN);
  k_scan<<<1, 1024, 0, stream>>>(cnt2, off2, N_IP);
  k_copyint<<<(N_CONN + N_IP + BT - 1) / BT, BT, 0, stream>>>(off1, cur1, N_CONN + N_IP);
  k_scatter<<<(NE + BT - 1) / BT, BT, 0, stream>>>(src1, dst1, src2, dst2,
                                                   cur1, cur2, srcs1, srcs2);

  dim3 gIP128((N_IP + 63) / 64, 2);
  dim3 gCN128((N_CONN + 63) / 64, 2);
  dim3 gIP384((N_IP + 63) / 64, 6);

  for (int t = 0; t < T_ROUNDS; t++) {
    // message 1 (ip -> conn): P1 = ip_state @ Wm1_top, Q1 = conn_state @ Wm1_bot
    gemm_bf16<0><<<gIP128, 256, 0, stream>>>(ip_state, Wm1, nullptr, P1, N_IP, 128);
    gemm_bf16<0><<<gCN128, 256, 0, stream>>>(conn_state, Wm1 + 128 * 128, nullptr, Q1, N_CONN, 128);
    k_gather_mean<<<(N_CONN * 32 + BT - 1) / BT, BT, 0, stream>>>(
        P1, Q1, bm1, srcs1, off1, cnt1, sum1, N_CONN);
    // message 2 (conn -> ip): P2 = conn_state @ Wm2_top, Q2 = ip_state @ Wm2_bot
    gemm_bf16<0><<<gCN128, 256, 0, stream>>>(conn_state, Wm2, nullptr, P2, N_CONN, 128);
    gemm_bf16<0><<<gIP128, 256, 0, stream>>>(ip_state, Wm2 + 128 * 128, nullptr, Q2, N_IP, 128);
    k_gather_mean<<<(N_IP * 32 + BT - 1) / BT, BT, 0, stream>>>(
        P2, Q2, bm2, srcs2, off2, cnt2, sum2, N_IP);

    // GRU ip: x = conn_mean (sum2), h = ip_state
    gemm_bf16<0><<<gIP384, 256, 0, stream>>>(sum2, gik, gib, gm1, N_IP, 384);
    gemm_bf16<0><<<gIP384, 256, 0, stream>>>(ip_state, gir, gib + 384, gm2, N_IP, 384);
    k_gru<<<(N_IP * D + BT - 1) / BT, BT, 0, stream>>>(gm1, gm2, ip_state, N_IP);

    // GRU conn: x = ip_mean (sum1), h = conn_state — chunked
    for (int base = 0; base < N_CONN; base += CHUNK) {
      int rows = (N_CONN - base < CHUNK) ? (N_CONN - base) : CHUNK;
      dim3 gc((rows + 63) / 64, 6);
      gemm_bf16<0><<<gc, 256, 0, stream>>>(sum1 + (size_t)base * D, gck, gcb, gm1, rows, 384);
      gemm_bf16<0><<<gc, 256, 0, stream>>>(conn_state + (size_t)base * D, gcr, gcb + 384, gm2, rows, 384);
      k_gru<<<(rows * D + BT - 1) / BT, BT, 0, stream>>>(gm1, gm2, conn_state + (size_t)base * D, rows);
    }
  }

  // readout
  gemm_bf16<1><<<gCN128, 256, 0, stream>>>(conn_state, Wr1, br1, h1, N_CONN, 128);
  dim3 gH2((N_CONN + 63) / 64, 1);
  gemm_bf16<1><<<gH2, 256, 0, stream>>>(h1, Wr2, br2, h2, N_CONN, 64);
  k_readout<<<(N_CONN + BT - 1) / BT, BT, 0, stream>>>(h2, Wr3, br3, out);
}

// Round 3
// 1464.226 us; speedup vs baseline: 3.2335x; 1.2293x over previous
//
#include <hip/hip_runtime.h>
#include <math.h>

#define D 128
#define NF 10
#define N_IP 20000
#define N_CONN 100000
#define NE 200000
#define T_ROUNDS 3

typedef unsigned short u16;
using bf16x8 = __attribute__((ext_vector_type(8))) short;
using floatx4 = __attribute__((ext_vector_type(4))) float;

__device__ inline u16 f2bf(float f) {
  union { float f; unsigned u; } v; v.f = f;
  unsigned u = v.u;
  return (u16)((u + 0x7fffu + ((u >> 16) & 1u)) >> 16);  // RNE
}

__device__ inline bf16x8 pack8(float4 a, float4 b) {
  bf16x8 r;
  r[0] = (short)f2bf(a.x); r[1] = (short)f2bf(a.y);
  r[2] = (short)f2bf(a.z); r[3] = (short)f2bf(a.w);
  r[4] = (short)f2bf(b.x); r[5] = (short)f2bf(b.y);
  r[6] = (short)f2bf(b.z); r[7] = (short)f2bf(b.w);
  return r;
}

// ---------------- utility kernels ----------------

__global__ void k_fill1(float* p, int n4) {
  int i = blockIdx.x * blockDim.x + threadIdx.x;
  if (i < n4) ((float4*)p)[i] = make_float4(1.f, 1.f, 1.f, 1.f);
}

__global__ void k_init_conn(float* __restrict__ cs, const float* __restrict__ feat) {
  int i = blockIdx.x * blockDim.x + threadIdx.x;  // over N_CONN*128
  if (i >= N_CONN * D) return;
  int r = i >> 7, j = i & 127;
  cs[i] = (j < NF) ? feat[r * NF + j] : 0.f;
}

__global__ void k_count(const int* __restrict__ d1, const int* __restrict__ d2,
                        int* __restrict__ c1, int* __restrict__ c2) {
  int e = blockIdx.x * blockDim.x + threadIdx.x;
  if (e >= NE) return;
  atomicAdd(&c1[d1[e]], 1);
  atomicAdd(&c2[d2[e]], 1);
}

// convert + transpose weight 128x384 fp32 -> [col][k] 384x128 bf16
__global__ void k_prep_w(const float* __restrict__ W, u16* __restrict__ Wb) {
  int i = blockIdx.x * blockDim.x + threadIdx.x;  // 384*128
  if (i >= 384 * 128) return;
  int col = i >> 7, k = i & 127;
  Wb[i] = f2bf(W[k * 384 + col]);
}

// ---------------- parallel 3-pass exclusive scan ----------------
// pass1: per-block (1024 elems) sums
__global__ void k_scan_part(const int* __restrict__ cnt, int* __restrict__ bsum, int n) {
  int t = threadIdx.x;  // 256
  int base = blockIdx.x * 1024 + t * 4;
  int s = 0;
#pragma unroll
  for (int i = 0; i < 4; i++) { int j = base + i; if (j < n) s += cnt[j]; }
  for (int d = 32; d > 0; d >>= 1) s += __shfl_xor(s, d, 64);
  __shared__ int wred[4];
  int lane = t & 63, wv = t >> 6;
  if (lane == 0) wred[wv] = s;
  __syncthreads();
  if (t == 0) bsum[blockIdx.x] = wred[0] + wred[1] + wred[2] + wred[3];
}

// pass2: single block exclusive-scan of bsum in place (m <= 256)
__global__ void k_scan_mid(int* __restrict__ bsum, int m) {
  int t = threadIdx.x;
  int v = (t < m) ? bsum[t] : 0;
  int lane = t & 63, wv = t >> 6;
  int x = v;
  for (int d = 1; d < 64; d <<= 1) { int y = __shfl_up(x, d, 64); if (lane >= d) x += y; }
  __shared__ int wsum[4];
  if (lane == 63) wsum[wv] = x;
  __syncthreads();
  int add = 0;
  for (int i = 0; i < wv; i++) add += wsum[i];
  int ex = add + x - v;
  if (t < m) bsum[t] = ex;
}

// pass3: write offsets
__global__ void k_scan_final(const int* __restrict__ cnt, const int* __restrict__ bsum,
                             int* __restrict__ off, int n) {
  int t = threadIdx.x;
  int base = blockIdx.x * 1024 + t * 4;
  int vals[4]; int s = 0;
#pragma unroll
  for (int i = 0; i < 4; i++) {
    int j = base + i;
    vals[i] = (j < n) ? cnt[j] : 0;
    s += vals[i];
  }
  int lane = t & 63, wv = t >> 6;
  int x = s;
  for (int d = 1; d < 64; d <<= 1) { int y = __shfl_up(x, d, 64); if (lane >= d) x += y; }
  __shared__ int wsum[4];
  if (lane == 63) wsum[wv] = x;
  __syncthreads();
  int add = 0;
  for (int i = 0; i < wv; i++) add += wsum[i];
  int run = add + x - s + bsum[blockIdx.x];
#pragma unroll
  for (int i = 0; i < 4; i++) {
    int j = base + i;
    if (j < n) off[j] = run;
    run += vals[i];
  }
}

__global__ void k_copyint(const int* __restrict__ a, int* __restrict__ b, int n) {
  int i = blockIdx.x * blockDim.x + threadIdx.x;
  if (i < n) b[i] = a[i];
}

// scatter src ids into dst-sorted order (both edge sets at once)
__global__ void k_scatter(const int* __restrict__ s1, const int* __restrict__ d1,
                          const int* __restrict__ s2, const int* __restrict__ d2,
                          int* __restrict__ cur1, int* __restrict__ cur2,
                          int* __restrict__ o1, int* __restrict__ o2) {
  int e = blockIdx.x * blockDim.x + threadIdx.x;
  if (e >= NE) return;
  int p1 = atomicAdd(&cur1[d1[e]], 1);
  o1[p1] = s1[e];
  int p2 = atomicAdd(&cur2[d2[e]], 1);
  o2[p2] = s2[e];
}

// ---------------- segment mean via gather: mean[n] = avg_e relu(P[src_e] + Q[n] + b) ----------------
__global__ void k_gather_mean(const float* __restrict__ P, const float* __restrict__ Q,
                              const float* __restrict__ bias, const int* __restrict__ srcs,
                              const int* __restrict__ off, const int* __restrict__ cnt,
                              float* __restrict__ outm, int nnodes) {
  int idx = blockIdx.x * blockDim.x + threadIdx.x;  // nnodes*32, 4 cols/lane
  int node = idx >> 5;
  if (node >= nnodes) return;
  int c4 = (idx & 31) << 2;
  float4 q = *(const float4*)(Q + (size_t)node * D + c4);
  float4 bb = *(const float4*)(bias + c4);
  float qx = q.x + bb.x, qy = q.y + bb.y, qz = q.z + bb.z, qw = q.w + bb.w;
  float ax = 0.f, ay = 0.f, az = 0.f, aw = 0.f;
  int o = off[node], n = cnt[node];
  for (int i = 0; i < n; i++) {
    int s = srcs[o + i];
    float4 p = *(const float4*)(P + (size_t)s * D + c4);
    ax += fmaxf(p.x + qx, 0.f);
    ay += fmaxf(p.y + qy, 0.f);
    az += fmaxf(p.z + qz, 0.f);
    aw += fmaxf(p.w + qw, 0.f);
  }
  float inv = 1.f / fmaxf((float)n, 1.f);
  *(float4*)(outm + (size_t)node * D + c4) =
      make_float4(ax * inv, ay * inv, az * inv, aw * inv);
}

// ---------------- fused GRU: h = GRU(x, h) in place ----------------
// Block: 64 rows, all 128 h-cols (4 chunks of 32). No LDS, no syncthreads:
// each wave owns 16 rows; A-frags preloaded to regs; B-frags read from
// pre-transposed bf16 weights ([col][k], L2-resident).
__global__ __launch_bounds__(256) void k_gru_fused(
    const float* __restrict__ X, const u16* __restrict__ Wxb,
    const u16* __restrict__ Whb, const float* __restrict__ bias,
    float* __restrict__ H, int rows) {
  const int tid = threadIdx.x, wv = tid >> 6, lane = tid & 63;
  const int lrow = lane & 15, quad = lane >> 4;
  const int bm = blockIdx.x * 64;
  const int arow = bm + wv * 16 + lrow;
  const bool arv = arow < rows;
  bf16x8 ax[4], ah[4];
  {
    const float* xp = X + (size_t)arow * 128 + quad * 8;
    const float* hp = H + (size_t)arow * 128 + quad * 8;
#pragma unroll
    for (int ks = 0; ks < 4; ks++) {
      float4 a0 = make_float4(0, 0, 0, 0), a1 = a0, b0 = a0, b1 = a0;
      if (arv) {
        a0 = *(const float4*)(xp + ks * 32);
        a1 = *(const float4*)(xp + ks * 32 + 4);
        b0 = *(const float4*)(hp + ks * 32);
        b1 = *(const float4*)(hp + ks * 32 + 4);
      }
      ax[ks] = pack8(a0, a1);
      ah[ks] = pack8(b0, b1);
    }
  }
  const int crow = bm + wv * 16 + quad * 4;  // + reg
#pragma unroll
  for (int ch = 0; ch < 4; ch++) {
    floatx4 accx[2][3], acch[2][3];
#pragma unroll
    for (int t = 0; t < 2; t++)
#pragma unroll
      for (int g = 0; g < 3; g++) {
        accx[t][g] = {0.f, 0.f, 0.f, 0.f};
        acch[t][g] = {0.f, 0.f, 0.f, 0.f};
      }
#pragma unroll
    for (int ks = 0; ks < 4; ks++) {
#pragma unroll
      for (int t = 0; t < 2; t++) {
#pragma unroll
        for (int g = 0; g < 3; g++) {
          int col = g * 128 + ch * 32 + t * 16 + lrow;
          bf16x8 bx = *(const bf16x8*)(Wxb + (size_t)col * 128 + quad * 8 + ks * 32);
          bf16x8 bh = *(const bf16x8*)(Whb + (size_t)col * 128 + quad * 8 + ks * 32);
          accx[t][g] = __builtin_amdgcn_mfma_f32_16x16x32_bf16(ax[ks], bx, accx[t][g], 0, 0, 0);
          acch[t][g] = __builtin_amdgcn_mfma_f32_16x16x32_bf16(ah[ks], bh, acch[t][g], 0, 0, 0);
        }
      }
    }
#pragma unroll
    for (int t = 0; t < 2; t++) {
      int hcol = ch * 32 + t * 16 + lrow;
      float bxz = bias[hcol];
      float bxr = bias[128 + hcol];
      float bxh = bias[256 + hcol];
      float bhz = bias[384 + hcol];
      float bhr = bias[384 + 128 + hcol];
      float bhh = bias[384 + 256 + hcol];
#pragma unroll
      for (int reg = 0; reg < 4; reg++) {
        int r = crow + reg;
        if (r < rows) {
          float xz = accx[t][0][reg] + bxz;
          float xr = accx[t][1][reg] + bxr;
          float xh = accx[t][2][reg] + bxh;
          float hz = acch[t][0][reg] + bhz;
          float hr = acch[t][1][reg] + bhr;
          float hh = acch[t][2][reg] + bhh;
          float z = 1.f / (1.f + expf(-(xz + hz)));
          float rr = 1.f / (1.f + expf(-(xr + hr)));
          float hc = tanhf(xh + rr * hh);
          float* hp2 = H + (size_t)r * 128 + hcol;
          float hold = *hp2;
          *hp2 = z * hold + (1.f - z) * hc;
        }
      }
    }
  }
}

// ---------------- bf16 MFMA GEMM: C[M,Nc] = act(A[M,128] @ W[128,Nc] + bias) ----------------
template <int RELU>
__global__ __launch_bounds__(256) void gemm_bf16(
    const float* __restrict__ A, const float* __restrict__ W,
    const float* __restrict__ bias, float* __restrict__ C, int M, int Nc) {
  constexpr int LDA = 136;
  __shared__ __align__(16) u16 As[64 * LDA];
  __shared__ __align__(16) u16 Bs[64 * LDA];  // Bs[n][k] = W[k][bn+n]
  const int bm = blockIdx.x * 64, bn = blockIdx.y * 64;
  const int tid = threadIdx.x;
#pragma unroll
  for (int i = 0; i < 8; i++) {  // A: 64x128 = 2048 float4
    int l = tid + i * 256;
    int r = l >> 5, c4 = (l & 31) << 2;
    int gr = bm + r;
    float4 v = make_float4(0, 0, 0, 0);
    if (gr < M) v = *(const float4*)(A + (size_t)gr * 128 + c4);
    u16* p = As + r * LDA + c4;
    p[0] = f2bf(v.x); p[1] = f2bf(v.y); p[2] = f2bf(v.z); p[3] = f2bf(v.w);
  }
#pragma unroll
  for (int i = 0; i < 8; i++) {  // W: 128x64 = 2048 float4, transpose into Bs
    int l = tid + i * 256;
    int k = l >> 4, n4 = (l & 15) << 2;
    float4 v = *(const float4*)(W + (size_t)k * Nc + bn + n4);
    Bs[(n4 + 0) * LDA + k] = f2bf(v.x);
    Bs[(n4 + 1) * LDA + k] = f2bf(v.y);
    Bs[(n4 + 2) * LDA + k] = f2bf(v.z);
    Bs[(n4 + 3) * LDA + k] = f2bf(v.w);
  }
  __syncthreads();
  const int wv = tid >> 6, lane = tid & 63;
  const int lrow = lane & 15, quad = lane >> 4;
  floatx4 acc[4] = {{0,0,0,0},{0,0,0,0},{0,0,0,0},{0,0,0,0}};
  const u16* arow = As + (wv * 16 + lrow) * LDA + quad * 8;
#pragma unroll
  for (int ks = 0; ks < 4; ks++) {
    bf16x8 af = *(const bf16x8*)(arow + ks * 32);
#pragma unroll
    for (int nt = 0; nt < 4; nt++) {
      bf16x8 bfr = *(const bf16x8*)(Bs + (nt * 16 + lrow) * LDA + quad * 8 + ks * 32);
      acc[nt] = __builtin_amdgcn_mfma_f32_16x16x32_bf16(af, bfr, acc[nt], 0, 0, 0);
    }
  }
#pragma unroll
  for (int nt = 0; nt < 4; nt++) {
    int col = bn + nt * 16 + lrow;
    float bv = bias ? bias[col] : 0.f;
#pragma unroll
    for (int reg = 0; reg < 4; reg++) {
      int gr = bm + wv * 16 + quad * 4 + reg;
      if (gr < M) {
        float v = acc[nt][reg] + bv;
        if (RELU) v = fmaxf(v, 0.f);
        C[(size_t)gr * Nc + col] = v;
      }
    }
  }
}

// ---------------- fused final layer: logits + softmax ----------------
__global__ void k_readout(const float* __restrict__ h2, const float* __restrict__ W3,
                          const float* __restrict__ b3, float* __restrict__ out) {
  __shared__ float w[64 * 15];
  __shared__ float b[15];
  for (int l = threadIdx.x; l < 960; l += blockDim.x) w[l] = W3[l];
  if (threadIdx.x < 15) b[threadIdx.x] = b3[threadIdx.x];
  __syncthreads();
  int r = blockIdx.x * blockDim.x + threadIdx.x;
  if (r >= N_CONN) return;
  float hv[64];
  const float4* hp = (const float4*)(h2 + (size_t)r * 64);
#pragma unroll
  for (int i = 0; i < 16; i++) {
    float4 v = hp[i];
    hv[4 * i] = v.x; hv[4 * i + 1] = v.y; hv[4 * i + 2] = v.z; hv[4 * i + 3] = v.w;
  }
  float lg[15];
#pragma unroll
  for (int c = 0; c < 15; c++) lg[c] = b[c];
  for (int k = 0; k < 64; k++) {
    float hk = hv[k];
#pragma unroll
    for (int c = 0; c < 15; c++) lg[c] += hk * w[k * 15 + c];
  }
  float m = lg[0];
#pragma unroll
  for (int c = 1; c < 15; c++) m = fmaxf(m, lg[c]);
  float ssum = 0.f;
#pragma unroll
  for (int c = 0; c < 15; c++) { lg[c] = expf(lg[c] - m); ssum += lg[c]; }
  float inv = 1.f / ssum;
#pragma unroll
  for (int c = 0; c < 15; c++) out[(size_t)r * 15 + c] = lg[c] * inv;
}

// ---------------- launch ----------------
extern "C" void kernel_launch(void* const* d_in, const int* in_sizes, int n_in,
                              void* d_out, int out_size, void* d_ws, size_t ws_size,
                              hipStream_t stream) {
  const float* feat = (const float*)d_in[0];
  const int* src1 = (const int*)d_in[1];
  const int* dst1 = (const int*)d_in[2];
  const int* src2 = (const int*)d_in[3];
  const int* dst2 = (const int*)d_in[4];
  const float* Wm1 = (const float*)d_in[5];
  const float* bm1 = (const float*)d_in[6];
  const float* Wm2 = (const float*)d_in[7];
  const float* bm2 = (const float*)d_in[8];
  const float* gik = (const float*)d_in[9];
  const float* gir = (const float*)d_in[10];
  const float* gib = (const float*)d_in[11];
  const float* gck = (const float*)d_in[12];
  const float* gcr = (const float*)d_in[13];
  const float* gcb = (const float*)d_in[14];
  const float* Wr1 = (const float*)d_in[15];
  const float* br1 = (const float*)d_in[16];
  const float* Wr2 = (const float*)d_in[17];
  const float* br2 = (const float*)d_in[18];
  const float* Wr3 = (const float*)d_in[19];
  const float* br3 = (const float*)d_in[20];
  float* out = (float*)d_out;

  // ---- workspace layout ----
  float* ws = (float*)d_ws;
  size_t o = 0;
  float* ip_state = ws + o;   o += (size_t)N_IP * D;
  float* conn_state = ws + o; o += (size_t)N_CONN * D;
  float* sum1 = ws + o;       o += (size_t)N_CONN * D;  // ip_mean (GRU-conn x)
  float* sum2 = ws + o;       o += (size_t)N_IP * D;    // conn_mean (GRU-ip x)
  float* R = ws + o;          o += (size_t)19200000;    // overlay
  // overlay A: P1 (N_IP*D), Q1 (N_CONN*D)
  float* P1 = R;
  float* Q1 = R + (size_t)N_IP * D;
  // overlay B: P2 (N_CONN*D), Q2 (N_IP*D)
  float* P2 = R;
  float* Q2 = R + (size_t)N_CONN * D;
  // overlay C (readout): h1 (N_CONN*128), h2 (N_CONN*64)
  float* h1 = R;
  float* h2 = R + (size_t)N_CONN * D;
  // bf16 pre-transposed GRU weights: 4 x 384*128 u16
  u16* wb = (u16*)(ws + o); o += 98304 / 1;  // 98304 floats? careful: 4*49152 u16 = 393216 B = 98304 floats
  u16* gikb = wb;
  u16* girb = wb + 49152;
  u16* gckb = wb + 2 * 49152;
  u16* gcrb = wb + 3 * 49152;
  // int region
  int* ip = (int*)(ws + o);
  int* cnt1 = ip;  ip += N_CONN;
  int* cnt2 = ip;  ip += N_IP;
  int* off1 = ip;  ip += N_CONN;
  int* off2 = ip;  ip += N_IP;
  int* cur1 = ip;  ip += N_CONN;
  int* cur2 = ip;  ip += N_IP;
  int* srcs1 = ip; ip += NE;
  int* srcs2 = ip; ip += NE;
  int* bsum1 = ip; ip += 256;
  int* bsum2 = ip; ip += 256;

  const int BT = 256;

  // ---- init states + weight prep ----
  k_fill1<<<(N_IP * D / 4 + BT - 1) / BT, BT, 0, stream>>>(ip_state, N_IP * D / 4);
  k_init_conn<<<(N_CONN * D + BT - 1) / BT, BT, 0, stream>>>(conn_state, feat);
  k_prep_w<<<(384 * 128 + BT - 1) / BT, BT, 0, stream>>>(gik, gikb);
  k_prep_w<<<(384 * 128 + BT - 1) / BT, BT, 0, stream>>>(gir, girb);
  k_prep_w<<<(384 * 128 + BT - 1) / BT, BT, 0, stream>>>(gck, gckb);
  k_prep_w<<<(384 * 128 + BT - 1) / BT, BT, 0, stream>>>(gcr, gcrb);

  // ---- build CSR ----
  hipMemsetAsync(cnt1, 0, (size_t)(N_CONN + N_IP) * sizeof(int), stream);
  k_count<<<(NE + BT - 1) / BT, BT, 0, stream>>>(dst1, dst2, cnt1, cnt2);
  const int nb1 = (N_CONN + 1023) / 1024, nb2 = (N_IP + 1023) / 1024;
  k_scan_part<<<nb1, 256, 0, stream>>>(cnt1, bsum1, N_CONN);
  k_scan_part<<<nb2, 256, 0, stream>>>(cnt2, bsum2, N_IP);
  k_scan_mid<<<1, 256, 0, stream>>>(bsum1, nb1);
  k_scan_mid<<<1, 256, 0, stream>>>(bsum2, nb2);
  k_scan_final<<<nb1, 256, 0, stream>>>(cnt1, bsum1, off1, N_CONN);
  k_scan_final<<<nb2, 256, 0, stream>>>(cnt2, bsum2, off2, N_IP);
  k_copyint<<<(N_CONN + N_IP + BT - 1) / BT, BT, 0, stream>>>(off1, cur1, N_CONN + N_IP);
  k_scatter<<<(NE + BT - 1) / BT, BT, 0, stream>>>(src1, dst1, src2, dst2,
                                                   cur1, cur2, srcs1, srcs2);

  dim3 gIP128((N_IP + 63) / 64, 2);
  dim3 gCN128((N_CONN + 63) / 64, 2);
  const int gGruIp = (N_IP + 63) / 64;
  const int gGruCn = (N_CONN + 63) / 64;

  for (int t = 0; t < T_ROUNDS; t++) {
    // message 1 (ip -> conn)
    gemm_bf16<0><<<gIP128, 256, 0, stream>>>(ip_state, Wm1, nullptr, P1, N_IP, 128);
    gemm_bf16<0><<<gCN128, 256, 0, stream>>>(conn_state, Wm1 + 128 * 128, nullptr, Q1, N_CONN, 128);
    k_gather_mean<<<(N_CONN * 32 + BT - 1) / BT, BT, 0, stream>>>(
        P1, Q1, bm1, srcs1, off1, cnt1, sum1, N_CONN);
    // message 2 (conn -> ip)
    gemm_bf16<0><<<gCN128, 256, 0, stream>>>(conn_state, Wm2, nullptr, P2, N_CONN, 128);
    gemm_bf16<0><<<gIP128, 256, 0, stream>>>(ip_state, Wm2 + 128 * 128, nullptr, Q2, N_IP, 128);
    k_gather_mean<<<(N_IP * 32 + BT - 1) / BT, BT, 0, stream>>>(
        P2, Q2, bm2, srcs2, off2, cnt2, sum2, N_IP);

    // fused GRUs (in-place state update, no scratch)
    k_gru_fused<<<gGruIp, 256, 0, stream>>>(sum2, gikb, girb, gib, ip_state, N_IP);
    k_gru_fused<<<gGruCn, 256, 0, stream>>>(sum1, gckb, gcrb, gcb, conn_state, N_CONN);
  }

  // readout
  gemm_bf16<1><<<gCN128, 256, 0, stream>>>(conn_state, Wr1, br1, h1, N_CONN, 128);
  dim3 gH2((N_CONN + 63) / 64, 1);
  gemm_bf16<1><<<gH2, 256, 0, stream>>>(h1, Wr2, br2, h2, N_CONN, 64);
  k_readout<<<(N_CONN + BT - 1) / BT, BT, 0, stream>>>(h2, Wr3, br3, out);
}

// Round 4
// 1073.464 us; speedup vs baseline: 4.4105x; 1.3640x over previous
//
#include <hip/hip_runtime.h>
#include <math.h>

#define D 128
#define NF 10
#define N_IP 20000
#define N_CONN 100000
#define NE 200000
#define T_ROUNDS 3

typedef unsigned short u16;
using bf16x8 = __attribute__((ext_vector_type(8))) short;
using floatx4 = __attribute__((ext_vector_type(4))) float;

__device__ inline u16 f2bf(float f) {
  union { float f; unsigned u; } v; v.f = f;
  unsigned u = v.u;
  return (u16)((u + 0x7fffu + ((u >> 16) & 1u)) >> 16);  // RNE
}

__device__ inline bf16x8 pack8(float4 a, float4 b) {
  bf16x8 r;
  r[0] = (short)f2bf(a.x); r[1] = (short)f2bf(a.y);
  r[2] = (short)f2bf(a.z); r[3] = (short)f2bf(a.w);
  r[4] = (short)f2bf(b.x); r[5] = (short)f2bf(b.y);
  r[6] = (short)f2bf(b.z); r[7] = (short)f2bf(b.w);
  return r;
}

// ---------------- utility kernels ----------------

__global__ void k_fill1(float* p, int n4) {
  int i = blockIdx.x * blockDim.x + threadIdx.x;
  if (i < n4) ((float4*)p)[i] = make_float4(1.f, 1.f, 1.f, 1.f);
}

__global__ void k_init_conn(float* __restrict__ cs, const float* __restrict__ feat) {
  int i = blockIdx.x * blockDim.x + threadIdx.x;
  if (i >= N_CONN * D) return;
  int r = i >> 7, j = i & 127;
  cs[i] = (j < NF) ? feat[r * NF + j] : 0.f;
}

__global__ void k_count(const int* __restrict__ d1, const int* __restrict__ d2,
                        int* __restrict__ c1, int* __restrict__ c2) {
  int e = blockIdx.x * blockDim.x + threadIdx.x;
  if (e >= NE) return;
  atomicAdd(&c1[d1[e]], 1);
  atomicAdd(&c2[d2[e]], 1);
}

// convert + transpose weight 128x384 fp32 -> [col][k] 384x128 bf16
__global__ void k_prep_w(const float* __restrict__ W, u16* __restrict__ Wb) {
  int i = blockIdx.x * blockDim.x + threadIdx.x;
  if (i >= 384 * 128) return;
  int col = i >> 7, k = i & 127;
  Wb[i] = f2bf(W[k * 384 + col]);
}

// ---------------- parallel 3-pass exclusive scan ----------------
__global__ void k_scan_part(const int* __restrict__ cnt, int* __restrict__ bsum, int n) {
  int t = threadIdx.x;  // 256
  int base = blockIdx.x * 1024 + t * 4;
  int s = 0;
#pragma unroll
  for (int i = 0; i < 4; i++) { int j = base + i; if (j < n) s += cnt[j]; }
  for (int d = 32; d > 0; d >>= 1) s += __shfl_xor(s, d, 64);
  __shared__ int wred[4];
  int lane = t & 63, wv = t >> 6;
  if (lane == 0) wred[wv] = s;
  __syncthreads();
  if (t == 0) bsum[blockIdx.x] = wred[0] + wred[1] + wred[2] + wred[3];
}

__global__ void k_scan_mid(int* __restrict__ bsum, int m) {
  int t = threadIdx.x;
  int v = (t < m) ? bsum[t] : 0;
  int lane = t & 63, wv = t >> 6;
  int x = v;
  for (int d = 1; d < 64; d <<= 1) { int y = __shfl_up(x, d, 64); if (lane >= d) x += y; }
  __shared__ int wsum[4];
  if (lane == 63) wsum[wv] = x;
  __syncthreads();
  int add = 0;
  for (int i = 0; i < wv; i++) add += wsum[i];
  int ex = add + x - v;
  if (t < m) bsum[t] = ex;
}

__global__ void k_scan_final(const int* __restrict__ cnt, const int* __restrict__ bsum,
                             int* __restrict__ off, int n) {
  int t = threadIdx.x;
  int base = blockIdx.x * 1024 + t * 4;
  int vals[4]; int s = 0;
#pragma unroll
  for (int i = 0; i < 4; i++) {
    int j = base + i;
    vals[i] = (j < n) ? cnt[j] : 0;
    s += vals[i];
  }
  int lane = t & 63, wv = t >> 6;
  int x = s;
  for (int d = 1; d < 64; d <<= 1) { int y = __shfl_up(x, d, 64); if (lane >= d) x += y; }
  __shared__ int wsum[4];
  if (lane == 63) wsum[wv] = x;
  __syncthreads();
  int add = 0;
  for (int i = 0; i < wv; i++) add += wsum[i];
  int run = add + x - s + bsum[blockIdx.x];
#pragma unroll
  for (int i = 0; i < 4; i++) {
    int j = base + i;
    if (j < n) off[j] = run;
    run += vals[i];
  }
}

__global__ void k_copyint(const int* __restrict__ a, int* __restrict__ b, int n) {
  int i = blockIdx.x * blockDim.x + threadIdx.x;
  if (i < n) b[i] = a[i];
}

__global__ void k_scatter(const int* __restrict__ s1, const int* __restrict__ d1,
                          const int* __restrict__ s2, const int* __restrict__ d2,
                          int* __restrict__ cur1, int* __restrict__ cur2,
                          int* __restrict__ o1, int* __restrict__ o2) {
  int e = blockIdx.x * blockDim.x + threadIdx.x;
  if (e >= NE) return;
  int p1 = atomicAdd(&cur1[d1[e]], 1);
  o1[p1] = s1[e];
  int p2 = atomicAdd(&cur2[d2[e]], 1);
  o2[p2] = s2[e];
}

// ---------------- segment mean via gather, MLP=4 ----------------
__global__ void k_gather_mean(const float* __restrict__ P, const float* __restrict__ Q,
                              const float* __restrict__ bias, const int* __restrict__ srcs,
                              const int* __restrict__ off, const int* __restrict__ cnt,
                              float* __restrict__ outm, int nnodes) {
  int idx = blockIdx.x * blockDim.x + threadIdx.x;  // nnodes*32, 4 cols/lane
  int node = idx >> 5;
  if (node >= nnodes) return;
  int c4 = (idx & 31) << 2;
  float4 q = *(const float4*)(Q + (size_t)node * D + c4);
  float4 bb = *(const float4*)(bias + c4);
  float qx = q.x + bb.x, qy = q.y + bb.y, qz = q.z + bb.z, qw = q.w + bb.w;
  float ax = 0.f, ay = 0.f, az = 0.f, aw = 0.f;
  int o = off[node], n = cnt[node];
  int i = 0;
  for (; i + 4 <= n; i += 4) {
    int s0 = srcs[o + i], s1 = srcs[o + i + 1], s2 = srcs[o + i + 2], s3 = srcs[o + i + 3];
    float4 p0 = *(const float4*)(P + (size_t)s0 * D + c4);
    float4 p1 = *(const float4*)(P + (size_t)s1 * D + c4);
    float4 p2 = *(const float4*)(P + (size_t)s2 * D + c4);
    float4 p3 = *(const float4*)(P + (size_t)s3 * D + c4);
    ax += fmaxf(p0.x + qx, 0.f) + fmaxf(p1.x + qx, 0.f) + fmaxf(p2.x + qx, 0.f) + fmaxf(p3.x + qx, 0.f);
    ay += fmaxf(p0.y + qy, 0.f) + fmaxf(p1.y + qy, 0.f) + fmaxf(p2.y + qy, 0.f) + fmaxf(p3.y + qy, 0.f);
    az += fmaxf(p0.z + qz, 0.f) + fmaxf(p1.z + qz, 0.f) + fmaxf(p2.z + qz, 0.f) + fmaxf(p3.z + qz, 0.f);
    aw += fmaxf(p0.w + qw, 0.f) + fmaxf(p1.w + qw, 0.f) + fmaxf(p2.w + qw, 0.f) + fmaxf(p3.w + qw, 0.f);
  }
  for (; i + 2 <= n; i += 2) {
    int s0 = srcs[o + i], s1 = srcs[o + i + 1];
    float4 p0 = *(const float4*)(P + (size_t)s0 * D + c4);
    float4 p1 = *(const float4*)(P + (size_t)s1 * D + c4);
    ax += fmaxf(p0.x + qx, 0.f) + fmaxf(p1.x + qx, 0.f);
    ay += fmaxf(p0.y + qy, 0.f) + fmaxf(p1.y + qy, 0.f);
    az += fmaxf(p0.z + qz, 0.f) + fmaxf(p1.z + qz, 0.f);
    aw += fmaxf(p0.w + qw, 0.f) + fmaxf(p1.w + qw, 0.f);
  }
  if (i < n) {
    int s0 = srcs[o + i];
    float4 p0 = *(const float4*)(P + (size_t)s0 * D + c4);
    ax += fmaxf(p0.x + qx, 0.f);
    ay += fmaxf(p0.y + qy, 0.f);
    az += fmaxf(p0.z + qz, 0.f);
    aw += fmaxf(p0.w + qw, 0.f);
  }
  float inv = 1.f / fmaxf((float)n, 1.f);
  *(float4*)(outm + (size_t)node * D + c4) =
      make_float4(ax * inv, ay * inv, az * inv, aw * inv);
}

// ---------------- fused GRU v2: LDS-staged weights ----------------
// Block: 64 rows, 4 waves (16 rows each). A-frags (x,h rows) preloaded to regs.
// Weights pre-transposed [col][k] bf16; per 32-col chunk, 6 segments (x/h x 3
// gates, 8KB each) staged to LDS (stride 136 u16 -> 2-way conflicts = free),
// MFMA B-frags via ds_read_b128. No early returns (syncthreads in loop).
__global__ __launch_bounds__(256) void k_gru_fused(
    const float* __restrict__ X, const u16* __restrict__ Wxb,
    const u16* __restrict__ Whb, const float* __restrict__ bias,
    float* __restrict__ H, int rows) {
  constexpr int LDC = 136;  // u16 stride per col (128 + 8 pad)
  __shared__ __align__(16) u16 Ls[6 * 32 * LDC];  // 52224 B
  const int tid = threadIdx.x, wv = tid >> 6, lane = tid & 63;
  const int lrow = lane & 15, quad = lane >> 4;
  const int bm = blockIdx.x * 64;
  const int arow = bm + wv * 16 + lrow;
  const bool arv = arow < rows;
  bf16x8 ax[4], ah[4];
  {
    const float* xp = X + (size_t)arow * 128 + quad * 8;
    const float* hp = H + (size_t)arow * 128 + quad * 8;
#pragma unroll
    for (int ks = 0; ks < 4; ks++) {
      float4 a0 = make_float4(0, 0, 0, 0), a1 = a0, b0 = a0, b1 = a0;
      if (arv) {
        a0 = *(const float4*)(xp + ks * 32);
        a1 = *(const float4*)(xp + ks * 32 + 4);
        b0 = *(const float4*)(hp + ks * 32);
        b1 = *(const float4*)(hp + ks * 32 + 4);
      }
      ax[ks] = pack8(a0, a1);
      ah[ks] = pack8(b0, b1);
    }
  }
  const int crow = bm + wv * 16 + quad * 4;
  const int scol = tid >> 4;             // staging col 0..15 (+16)
  const int sk = (tid & 15) * 8;         // staging k offset
  for (int ch = 0; ch < 4; ch++) {
    __syncthreads();  // previous chunk's LDS readers done
    uint4 v[12];
#pragma unroll
    for (int seg = 0; seg < 6; seg++) {  // all loads first (MLP)
      const u16* gsrc = (seg < 3 ? Wxb : Whb) +
                        ((size_t)((seg % 3) * 128 + ch * 32) * 128);
      v[2 * seg] = *(const uint4*)(gsrc + scol * 128 + sk);
      v[2 * seg + 1] = *(const uint4*)(gsrc + (scol + 16) * 128 + sk);
    }
#pragma unroll
    for (int seg = 0; seg < 6; seg++) {
      u16* ldst = Ls + seg * 32 * LDC;
      *(uint4*)(ldst + scol * LDC + sk) = v[2 * seg];
      *(uint4*)(ldst + (scol + 16) * LDC + sk) = v[2 * seg + 1];
    }
    __syncthreads();
    floatx4 accx[2][3], acch[2][3];
#pragma unroll
    for (int t = 0; t < 2; t++)
#pragma unroll
      for (int g = 0; g < 3; g++) {
        accx[t][g] = {0.f, 0.f, 0.f, 0.f};
        acch[t][g] = {0.f, 0.f, 0.f, 0.f};
      }
#pragma unroll
    for (int ks = 0; ks < 4; ks++) {
#pragma unroll
      for (int t = 0; t < 2; t++) {
#pragma unroll
        for (int g = 0; g < 3; g++) {
          const u16* bp = Ls + (size_t)(g * 32 + t * 16 + lrow) * LDC + quad * 8 + ks * 32;
          bf16x8 bx = *(const bf16x8*)(bp);
          bf16x8 bh = *(const bf16x8*)(bp + 3 * 32 * LDC);
          accx[t][g] = __builtin_amdgcn_mfma_f32_16x16x32_bf16(ax[ks], bx, accx[t][g], 0, 0, 0);
          acch[t][g] = __builtin_amdgcn_mfma_f32_16x16x32_bf16(ah[ks], bh, acch[t][g], 0, 0, 0);
        }
      }
    }
#pragma unroll
    for (int t = 0; t < 2; t++) {
      int hcol = ch * 32 + t * 16 + lrow;
      float bxz = bias[hcol];
      float bxr = bias[128 + hcol];
      float bxh = bias[256 + hcol];
      float bhz = bias[384 + hcol];
      float bhr = bias[384 + 128 + hcol];
      float bhh = bias[384 + 256 + hcol];
#pragma unroll
      for (int reg = 0; reg < 4; reg++) {
        int r = crow + reg;
        if (r < rows) {
          float xz = accx[t][0][reg] + bxz;
          float xr = accx[t][1][reg] + bxr;
          float xh = accx[t][2][reg] + bxh;
          float hz = acch[t][0][reg] + bhz;
          float hr = acch[t][1][reg] + bhr;
          float hh = acch[t][2][reg] + bhh;
          float z = 1.f / (1.f + expf(-(xz + hz)));
          float rr = 1.f / (1.f + expf(-(xr + hr)));
          float hc = tanhf(xh + rr * hh);
          float* hp2 = H + (size_t)r * 128 + hcol;
          float hold = *hp2;
          *hp2 = z * hold + (1.f - z) * hc;
        }
      }
    }
  }
}

// ---------------- bf16 MFMA GEMM: C[M,Nc] = act(A[M,128] @ W[128,Nc] + bias) ----------------
template <int RELU>
__global__ __launch_bounds__(256) void gemm_bf16(
    const float* __restrict__ A, const float* __restrict__ W,
    const float* __restrict__ bias, float* __restrict__ C, int M, int Nc) {
  constexpr int LDA = 136;
  __shared__ __align__(16) u16 As[64 * LDA];
  __shared__ __align__(16) u16 Bs[64 * LDA];
  const int bm = blockIdx.x * 64, bn = blockIdx.y * 64;
  const int tid = threadIdx.x;
#pragma unroll
  for (int i = 0; i < 8; i++) {
    int l = tid + i * 256;
    int r = l >> 5, c4 = (l & 31) << 2;
    int gr = bm + r;
    float4 v = make_float4(0, 0, 0, 0);
    if (gr < M) v = *(const float4*)(A + (size_t)gr * 128 + c4);
    u16* p = As + r * LDA + c4;
    p[0] = f2bf(v.x); p[1] = f2bf(v.y); p[2] = f2bf(v.z); p[3] = f2bf(v.w);
  }
#pragma unroll
  for (int i = 0; i < 8; i++) {
    int l = tid + i * 256;
    int k = l >> 4, n4 = (l & 15) << 2;
    float4 v = *(const float4*)(W + (size_t)k * Nc + bn + n4);
    Bs[(n4 + 0) * LDA + k] = f2bf(v.x);
    Bs[(n4 + 1) * LDA + k] = f2bf(v.y);
    Bs[(n4 + 2) * LDA + k] = f2bf(v.z);
    Bs[(n4 + 3) * LDA + k] = f2bf(v.w);
  }
  __syncthreads();
  const int wv = tid >> 6, lane = tid & 63;
  const int lrow = lane & 15, quad = lane >> 4;
  floatx4 acc[4] = {{0,0,0,0},{0,0,0,0},{0,0,0,0},{0,0,0,0}};
  const u16* arow = As + (wv * 16 + lrow) * LDA + quad * 8;
#pragma unroll
  for (int ks = 0; ks < 4; ks++) {
    bf16x8 af = *(const bf16x8*)(arow + ks * 32);
#pragma unroll
    for (int nt = 0; nt < 4; nt++) {
      bf16x8 bfr = *(const bf16x8*)(Bs + (nt * 16 + lrow) * LDA + quad * 8 + ks * 32);
      acc[nt] = __builtin_amdgcn_mfma_f32_16x16x32_bf16(af, bfr, acc[nt], 0, 0, 0);
    }
  }
#pragma unroll
  for (int nt = 0; nt < 4; nt++) {
    int col = bn + nt * 16 + lrow;
    float bv = bias ? bias[col] : 0.f;
#pragma unroll
    for (int reg = 0; reg < 4; reg++) {
      int gr = bm + wv * 16 + quad * 4 + reg;
      if (gr < M) {
        float v = acc[nt][reg] + bv;
        if (RELU) v = fmaxf(v, 0.f);
        C[(size_t)gr * Nc + col] = v;
      }
    }
  }
}

// ---------------- fused final layer: logits + softmax ----------------
__global__ void k_readout(const float* __restrict__ h2, const float* __restrict__ W3,
                          const float* __restrict__ b3, float* __restrict__ out) {
  __shared__ float w[64 * 15];
  __shared__ float b[15];
  for (int l = threadIdx.x; l < 960; l += blockDim.x) w[l] = W3[l];
  if (threadIdx.x < 15) b[threadIdx.x] = b3[threadIdx.x];
  __syncthreads();
  int r = blockIdx.x * blockDim.x + threadIdx.x;
  if (r >= N_CONN) return;
  float hv[64];
  const float4* hp = (const float4*)(h2 + (size_t)r * 64);
#pragma unroll
  for (int i = 0; i < 16; i++) {
    float4 v = hp[i];
    hv[4 * i] = v.x; hv[4 * i + 1] = v.y; hv[4 * i + 2] = v.z; hv[4 * i + 3] = v.w;
  }
  float lg[15];
#pragma unroll
  for (int c = 0; c < 15; c++) lg[c] = b[c];
  for (int k = 0; k < 64; k++) {
    float hk = hv[k];
#pragma unroll
    for (int c = 0; c < 15; c++) lg[c] += hk * w[k * 15 + c];
  }
  float m = lg[0];
#pragma unroll
  for (int c = 1; c < 15; c++) m = fmaxf(m, lg[c]);
  float ssum = 0.f;
#pragma unroll
  for (int c = 0; c < 15; c++) { lg[c] = expf(lg[c] - m); ssum += lg[c]; }
  float inv = 1.f / ssum;
#pragma unroll
  for (int c = 0; c < 15; c++) out[(size_t)r * 15 + c] = lg[c] * inv;
}

// ---------------- launch ----------------
extern "C" void kernel_launch(void* const* d_in, const int* in_sizes, int n_in,
                              void* d_out, int out_size, void* d_ws, size_t ws_size,
                              hipStream_t stream) {
  const float* feat = (const float*)d_in[0];
  const int* src1 = (const int*)d_in[1];
  const int* dst1 = (const int*)d_in[2];
  const int* src2 = (const int*)d_in[3];
  const int* dst2 = (const int*)d_in[4];
  const float* Wm1 = (const float*)d_in[5];
  const float* bm1 = (const float*)d_in[6];
  const float* Wm2 = (const float*)d_in[7];
  const float* bm2 = (const float*)d_in[8];
  const float* gik = (const float*)d_in[9];
  const float* gir = (const float*)d_in[10];
  const float* gib = (const float*)d_in[11];
  const float* gck = (const float*)d_in[12];
  const float* gcr = (const float*)d_in[13];
  const float* gcb = (const float*)d_in[14];
  const float* Wr1 = (const float*)d_in[15];
  const float* br1 = (const float*)d_in[16];
  const float* Wr2 = (const float*)d_in[17];
  const float* br2 = (const float*)d_in[18];
  const float* Wr3 = (const float*)d_in[19];
  const float* br3 = (const float*)d_in[20];
  float* out = (float*)d_out;

  // ---- workspace layout ----
  float* ws = (float*)d_ws;
  size_t o = 0;
  float* ip_state = ws + o;   o += (size_t)N_IP * D;
  float* conn_state = ws + o; o += (size_t)N_CONN * D;
  float* sum1 = ws + o;       o += (size_t)N_CONN * D;
  float* sum2 = ws + o;       o += (size_t)N_IP * D;
  float* R = ws + o;          o += (size_t)19200000;
  float* P1 = R;
  float* Q1 = R + (size_t)N_IP * D;
  float* P2 = R;
  float* Q2 = R + (size_t)N_CONN * D;
  float* h1 = R;
  float* h2 = R + (size_t)N_CONN * D;
  u16* wb = (u16*)(ws + o); o += 98304;  // 4 x 49152 u16 = 393216 B
  u16* gikb = wb;
  u16* girb = wb + 49152;
  u16* gckb = wb + 2 * 49152;
  u16* gcrb = wb + 3 * 49152;
  int* ip = (int*)(ws + o);
  int* cnt1 = ip;  ip += N_CONN;
  int* cnt2 = ip;  ip += N_IP;
  int* off1 = ip;  ip += N_CONN;
  int* off2 = ip;  ip += N_IP;
  int* cur1 = ip;  ip += N_CONN;
  int* cur2 = ip;  ip += N_IP;
  int* srcs1 = ip; ip += NE;
  int* srcs2 = ip; ip += NE;
  int* bsum1 = ip; ip += 256;
  int* bsum2 = ip; ip += 256;

  const int BT = 256;

  // ---- init states + weight prep ----
  k_fill1<<<(N_IP * D / 4 + BT - 1) / BT, BT, 0, stream>>>(ip_state, N_IP * D / 4);
  k_init_conn<<<(N_CONN * D + BT - 1) / BT, BT, 0, stream>>>(conn_state, feat);
  k_prep_w<<<(384 * 128 + BT - 1) / BT, BT, 0, stream>>>(gik, gikb);
  k_prep_w<<<(384 * 128 + BT - 1) / BT, BT, 0, stream>>>(gir, girb);
  k_prep_w<<<(384 * 128 + BT - 1) / BT, BT, 0, stream>>>(gck, gckb);
  k_prep_w<<<(384 * 128 + BT - 1) / BT, BT, 0, stream>>>(gcr, gcrb);

  // ---- build CSR ----
  hipMemsetAsync(cnt1, 0, (size_t)(N_CONN + N_IP) * sizeof(int), stream);
  k_count<<<(NE + BT - 1) / BT, BT, 0, stream>>>(dst1, dst2, cnt1, cnt2);
  const int nb1 = (N_CONN + 1023) / 1024, nb2 = (N_IP + 1023) / 1024;
  k_scan_part<<<nb1, 256, 0, stream>>>(cnt1, bsum1, N_CONN);
  k_scan_part<<<nb2, 256, 0, stream>>>(cnt2, bsum2, N_IP);
  k_scan_mid<<<1, 256, 0, stream>>>(bsum1, nb1);
  k_scan_mid<<<1, 256, 0, stream>>>(bsum2, nb2);
  k_scan_final<<<nb1, 256, 0, stream>>>(cnt1, bsum1, off1, N_CONN);
  k_scan_final<<<nb2, 256, 0, stream>>>(cnt2, bsum2, off2, N_IP);
  k_copyint<<<(N_CONN + N_IP + BT - 1) / BT, BT, 0, stream>>>(off1, cur1, N_CONN + N_IP);
  k_scatter<<<(NE + BT - 1) / BT, BT, 0, stream>>>(src1, dst1, src2, dst2,
                                                   cur1, cur2, srcs1, srcs2);

  dim3 gIP128((N_IP + 63) / 64, 2);
  dim3 gCN128((N_CONN + 63) / 64, 2);
  const int gGruIp = (N_IP + 63) / 64;
  const int gGruCn = (N_CONN + 63) / 64;

  for (int t = 0; t < T_ROUNDS; t++) {
    gemm_bf16<0><<<gIP128, 256, 0, stream>>>(ip_state, Wm1, nullptr, P1, N_IP, 128);
    gemm_bf16<0><<<gCN128, 256, 0, stream>>>(conn_state, Wm1 + 128 * 128, nullptr, Q1, N_CONN, 128);
    k_gather_mean<<<(N_CONN * 32 + BT - 1) / BT, BT, 0, stream>>>(
        P1, Q1, bm1, srcs1, off1, cnt1, sum1, N_CONN);
    gemm_bf16<0><<<gCN128, 256, 0, stream>>>(conn_state, Wm2, nullptr, P2, N_CONN, 128);
    gemm_bf16<0><<<gIP128, 256, 0, stream>>>(ip_state, Wm2 + 128 * 128, nullptr, Q2, N_IP, 128);
    k_gather_mean<<<(N_IP * 32 + BT - 1) / BT, BT, 0, stream>>>(
        P2, Q2, bm2, srcs2, off2, cnt2, sum2, N_IP);

    k_gru_fused<<<gGruIp, 256, 0, stream>>>(sum2, gikb, girb, gib, ip_state, N_IP);
    k_gru_fused<<<gGruCn, 256, 0, stream>>>(sum1, gckb, gcrb, gcb, conn_state, N_CONN);
  }

  gemm_bf16<1><<<gCN128, 256, 0, stream>>>(conn_state, Wr1, br1, h1, N_CONN, 128);
  dim3 gH2((N_CONN + 63) / 64, 1);
  gemm_bf16<1><<<gH2, 256, 0, stream>>>(h1, Wr2, br2, h2, N_CONN, 64);
  k_readout<<<(N_CONN + BT - 1) / BT, BT, 0, stream>>>(h2, Wr3, br3, out);
}